// Round 8
// baseline (387.335 us; speedup 1.0000x reference)
//
#include <hip/hip_runtime.h>
#include <hip/hip_bf16.h>
#include <stdint.h>

#define BATCH  16384
#define GAMMA  0.01f

using f32x4  = __attribute__((ext_vector_type(4))) float;
using bf16x8 = __attribute__((ext_vector_type(8))) __bf16;

#define MFMA16(a, b, c) __builtin_amdgcn_mfma_f32_16x16x32_bf16((a), (b), (c), 0, 0, 0)
#define BAR() asm volatile("s_barrier" ::: "memory")

// ---------- helpers ----------
__device__ __forceinline__ unsigned short f2bf(float f) {
  unsigned int u = __float_as_uint(f);
  unsigned int r = (u + 0x7fffu + ((u >> 16) & 1u)) >> 16;  // RNE
  return (unsigned short)r;
}
__device__ __forceinline__ float bf2f(unsigned short u) {
  return __uint_as_float(((unsigned int)u) << 16);
}
__device__ __forceinline__ float sigmoidf_(float x) {
  return 1.0f / (1.0f + __expf(-x));
}
__device__ __forceinline__ float tanhf_(float x) {
  float e = __expf(2.0f * x);
  return (e - 1.0f) / (e + 1.0f);
}
__device__ __forceinline__ void gload_lds16(const void* gsrc, void* ldst) {
  __builtin_amdgcn_global_load_lds(
      (const __attribute__((address_space(1))) void*)gsrc,
      (__attribute__((address_space(3))) void*)ldst, 16, 0, 0);
}

// =====================================================================
// 256x256 GEMM core, register-software-pipelined (R8).
// Insight (R2..R7 all ~900-945 TF): LDS-read work (~2300 cy/CU/K-tile)
// ~= MFMA work (~2480 cy/SIMD/K-tile); any schedule where a phase's
// MFMAs wait on reads issued IN that phase serializes the two pipes.
// Fix: frags double-buffered in regs; each phase issues reads for a
// LATER quadrant, then MFMAs on regs already loaded -> LDS pipe drains
// under the MFMA cluster (phase = max, not sum).
//   P1: stage A1(T+1)->cn; read B23(c);  Q0 = aLo x b01   ; BAR
//   P2: stage B0(T+1)->cn; read aHi(c);  Q1 = aLo x b23   ; BAR
//   P3: stage B1(T+1)->cn; (no reads)    Q2 = aHi x b01   ; BAR
//   P4: stage A0(T+2)->c;  vmcnt(2|0); BAR;   <- all T+1 staging done
//       read-ahead aLo,b01(T+1) from cn; Q3 = aHi x b23   ; (no BAR)
// Read-ahead is safe ONLY after the mid-P4 barrier (other waves'
// gload_lds completion is proven by their vmcnt before that barrier).
// Region-death audit: cn.A1 staged at P1(T) -- last readers (aLo/aHi
// of T-1) completed before end-P3(T-1) barrier; c.A0 staged at P4 --
// its readers ran at P4(T-1)/P2(T); B regions likewise. Slip <= 1
// phase (end barriers P1-P3, mid-P4).
// =====================================================================
#define GEMM_PREAMBLE_AND_KLOOP(X_, W_, lda_, K_, N_)                          \
  __shared__ unsigned short As[2 * 16384];                                     \
  __shared__ unsigned short Bs[2 * 16384];                                     \
  const int qq  = gridDim.x >> 3;                                              \
  const int swz = (blockIdx.x & 7) * qq + (blockIdx.x >> 3);                   \
  const int tiles_n = (N_) >> 8;                                               \
  const int brow = swz / tiles_n;                                              \
  const int bcol = swz % tiles_n;                                              \
  const int t    = threadIdx.x;                                                \
  const int lane = t & 63;                                                     \
  const int wave = t >> 6;                                                     \
  const int wm   = wave >> 2;                                                  \
  const int wn   = wave & 3;                                                   \
  const int lr   = lane & 15;                                                  \
  const int kq8  = (lane >> 4) * 8;                                            \
  const int sx   = (lr & 7) << 3;                                              \
  const int koff0 = kq8 ^ sx;                                                  \
  const int koff1 = (32 + kq8) ^ sx;                                           \
  const int aBase = (wm * 128 + lr) * 64;                                      \
  const int bBase = (wn * 64 + lr) * 64;                                       \
  const int srow = t >> 3;                                                     \
  const int sg   = (t & 7) ^ (srow & 7);                                       \
  const unsigned short* aSrc = (X_) + (size_t)(brow * 256 + srow) * (lda_) + sg * 8; \
  const unsigned short* bSrc = (W_) + (size_t)(bcol * 256 + srow) * (K_) + sg * 8;   \
  const int wofs = wave * 512;                                                 \
  auto STAGE_A = [&](int buf, int h, int k0) {                                 \
    gload_lds16(aSrc + (size_t)(h * 128) * (lda_) + k0,                        \
                As + buf * 16384 + (h * 128) * 64 + wofs);                     \
    gload_lds16(aSrc + (size_t)(h * 128 + 64) * (lda_) + k0,                   \
                As + buf * 16384 + (h * 128 + 64) * 64 + wofs);                \
  };                                                                           \
  auto STAGE_B = [&](int buf, int h, int k0) {                                 \
    gload_lds16(bSrc + (size_t)(h * 128) * (K_) + k0,                          \
                Bs + buf * 16384 + (h * 128) * 64 + wofs);                     \
    gload_lds16(bSrc + (size_t)(h * 128 + 64) * (K_) + k0,                     \
                Bs + buf * 16384 + (h * 128 + 64) * 64 + wofs);                \
  };                                                                           \
  f32x4 acc[8][4] = {};                                                        \
  bf16x8 aLo[4][2], aHi[4][2], bRg[4][2];                                      \
  const int nt = (K_) >> 6;                                                    \
  /* prologue: tile0 full + A0(1); force tile0; preload aLo/b01 of tile0 */    \
  STAGE_A(0, 0, 0); STAGE_A(0, 1, 0); STAGE_B(0, 0, 0); STAGE_B(0, 1, 0);      \
  STAGE_A(1, 0, 64);                                                           \
  asm volatile("s_waitcnt vmcnt(2)" ::: "memory");                             \
  BAR();                                                                       \
  _Pragma("unroll")                                                            \
  for (int i = 0; i < 4; ++i) {                                                \
    aLo[i][0] = *(const bf16x8*)(As + aBase + i * 1024 + koff0);               \
    aLo[i][1] = *(const bf16x8*)(As + aBase + i * 1024 + koff1);               \
  }                                                                            \
  _Pragma("unroll")                                                            \
  for (int j = 0; j < 2; ++j) {                                                \
    bRg[j][0] = *(const bf16x8*)(Bs + bBase + j * 1024 + koff0);               \
    bRg[j][1] = *(const bf16x8*)(Bs + bBase + j * 1024 + koff1);               \
  }                                                                            \
  for (int T = 0; T < nt; ++T) {                                               \
    const int c  = T & 1;                                                      \
    const int cn = c ^ 1;                                                      \
    const int k1 = (T + 1) << 6;                                               \
    const int k2 = (T + 2) << 6;                                               \
    const unsigned short* Ac = As + c * 16384;                                 \
    const unsigned short* Bc = Bs + c * 16384;                                 \
    const unsigned short* An = As + cn * 16384;                                \
    const unsigned short* Bn = Bs + cn * 16384;                                \
    /* P1: read B23; Q0 = aLo x b01 */                                         \
    if (T + 1 < nt) STAGE_A(cn, 1, k1);                                        \
    _Pragma("unroll")                                                          \
    for (int j = 2; j < 4; ++j) {                                              \
      bRg[j][0] = *(const bf16x8*)(Bc + bBase + j * 1024 + koff0);             \
      bRg[j][1] = *(const bf16x8*)(Bc + bBase + j * 1024 + koff1);             \
    }                                                                          \
    __builtin_amdgcn_s_setprio(1);                                             \
    _Pragma("unroll")                                                          \
    for (int i = 0; i < 4; ++i)                                                \
      _Pragma("unroll")                                                        \
      for (int j = 0; j < 2; ++j) {                                            \
        acc[i][j] = MFMA16(aLo[i][0], bRg[j][0], acc[i][j]);                   \
        acc[i][j] = MFMA16(aLo[i][1], bRg[j][1], acc[i][j]);                   \
      }                                                                        \
    __builtin_amdgcn_s_setprio(0);                                             \
    BAR();                                                                     \
    /* P2: read aHi; Q1 = aLo x b23 */                                         \
    if (T + 1 < nt) STAGE_B(cn, 0, k1);                                        \
    _Pragma("unroll")                                                          \
    for (int i = 0; i < 4; ++i) {                                              \
      aHi[i][0] = *(const bf16x8*)(Ac + aBase + (i + 4) * 1024 + koff0);       \
      aHi[i][1] = *(const bf16x8*)(Ac + aBase + (i + 4) * 1024 + koff1);       \
    }                                                                          \
    __builtin_amdgcn_s_setprio(1);                                             \
    _Pragma("unroll")                                                          \
    for (int i = 0; i < 4; ++i)                                                \
      _Pragma("unroll")                                                        \
      for (int j = 2; j < 4; ++j) {                                            \
        acc[i][j] = MFMA16(aLo[i][0], bRg[j][0], acc[i][j]);                   \
        acc[i][j] = MFMA16(aLo[i][1], bRg[j][1], acc[i][j]);                   \
      }                                                                        \
    __builtin_amdgcn_s_setprio(0);                                             \
    BAR();                                                                     \
    /* P3: no reads; Q2 = aHi x b01 */                                         \
    if (T + 1 < nt) STAGE_B(cn, 1, k1);                                        \
    __builtin_amdgcn_s_setprio(1);                                             \
    _Pragma("unroll")                                                          \
    for (int i = 0; i < 4; ++i)                                                \
      _Pragma("unroll")                                                        \
      for (int j = 0; j < 2; ++j) {                                            \
        acc[i + 4][j] = MFMA16(aHi[i][0], bRg[j][0], acc[i + 4][j]);           \
        acc[i + 4][j] = MFMA16(aHi[i][1], bRg[j][1], acc[i + 4][j]);           \
      }                                                                        \
    __builtin_amdgcn_s_setprio(0);                                             \
    BAR();                                                                     \
    /* P4: stage A0(T+2); vmcnt; BAR; read-ahead aLo/b01(T+1); Q3 */           \
    if (T + 2 < nt) {                                                          \
      STAGE_A(c, 0, k2);                                                       \
      asm volatile("s_waitcnt vmcnt(2)" ::: "memory");                         \
    } else {                                                                   \
      asm volatile("s_waitcnt vmcnt(0)" ::: "memory");                         \
    }                                                                          \
    BAR();                                                                     \
    if (T + 1 < nt) {                                                          \
      _Pragma("unroll")                                                        \
      for (int i = 0; i < 4; ++i) {                                            \
        aLo[i][0] = *(const bf16x8*)(An + aBase + i * 1024 + koff0);           \
        aLo[i][1] = *(const bf16x8*)(An + aBase + i * 1024 + koff1);           \
      }                                                                        \
      _Pragma("unroll")                                                        \
      for (int j = 0; j < 2; ++j) {                                            \
        bRg[j][0] = *(const bf16x8*)(Bn + bBase + j * 1024 + koff0);           \
        bRg[j][1] = *(const bf16x8*)(Bn + bBase + j * 1024 + koff1);           \
      }                                                                        \
    }                                                                          \
    __builtin_amdgcn_s_setprio(1);                                             \
    _Pragma("unroll")                                                          \
    for (int i = 0; i < 4; ++i)                                                \
      _Pragma("unroll")                                                        \
      for (int j = 2; j < 4; ++j) {                                            \
        acc[i + 4][j] = MFMA16(aHi[i][0], bRg[j][0], acc[i + 4][j]);           \
        acc[i + 4][j] = MFMA16(aHi[i][1], bRg[j][1], acc[i + 4][j]);           \
      }                                                                        \
    __builtin_amdgcn_s_setprio(0);                                             \
  }                                                                            \
  const int rbase = brow * 256 + wm * 128 + (lane >> 4) * 4;                   \
  const int cbase = bcol * 256 + wn * 64 + lr;

// ---------- GEMM1: Zs = sigmoid(Xcat @ Wcat^T + bias) ----------
__global__ __launch_bounds__(512, 2) void gemm_sig(
    const unsigned short* __restrict__ X, const unsigned short* __restrict__ W,
    unsigned short* __restrict__ C, int lda, int K, int N,
    const float* __restrict__ bz, const float* __restrict__ br) {
  GEMM_PREAMBLE_AND_KLOOP(X, W, lda, K, N)
  const float* bias = (bcol * 256 < 1024) ? bz : (br - 1024);  // bias[col] valid
#pragma unroll
  for (int i = 0; i < 8; ++i)
#pragma unroll
    for (int j = 0; j < 4; ++j)
#pragma unroll
      for (int q = 0; q < 4; ++q) {
        const int col = cbase + j * 16;
        C[(size_t)(rbase + i * 16 + q) * N + col] =
            f2bf(sigmoidf_(acc[i][j][q] + bias[col]));
      }
}

// ---------- GEMM23 merged: acc = [x|Hr] @ [Vh|A]^T  (K=2048, N=1024) --------
// out = h + eps * Zs_z * tanh(acc + bh)
__global__ __launch_bounds__(512, 2) void gemm_combine2(
    const unsigned short* __restrict__ X, const unsigned short* __restrict__ W,
    int lda, int K, int N,
    const unsigned short* __restrict__ Zs,
    const float* __restrict__ bh, const float* __restrict__ h,
    const float* __restrict__ epsp, float* __restrict__ fout) {
  GEMM_PREAMBLE_AND_KLOOP(X, W, lda, K, N)
  const float eps = epsp[0];
#pragma unroll
  for (int i = 0; i < 8; ++i)
#pragma unroll
    for (int j = 0; j < 4; ++j)
#pragma unroll
      for (int q = 0; q < 4; ++q) {
        const int row = rbase + i * 16 + q;
        const int col = cbase + j * 16;
        const size_t e = (size_t)row * 1024 + col;
        const float tv = tanhf_(acc[i][j][q] + bh[col]);
        fout[e] = h[e] + eps * bf2f(Zs[(size_t)row * 2048 + col]) * tv;
      }
}

// ---------- prep kernels ----------
__global__ void prep_x_kernel(const float* __restrict__ x, const float* __restrict__ h,
                              unsigned short* __restrict__ Xcat) {
  const int total4 = BATCH * 2048 / 4;
  for (int i = blockIdx.x * blockDim.x + threadIdx.x; i < total4; i += gridDim.x * blockDim.x) {
    const int e = i * 4;
    const int m = e >> 11;
    const int c = e & 2047;
    float4 v = (c < 1024) ? *(const float4*)(x + (size_t)m * 1024 + c)
                          : *(const float4*)(h + (size_t)m * 1024 + (c - 1024));
    ushort4 o;
    o.x = f2bf(v.x); o.y = f2bf(v.y); o.z = f2bf(v.z); o.w = f2bf(v.w);
    *(ushort4*)(Xcat + e) = o;
  }
}

__global__ void prep_wcat_kernel(const float* __restrict__ Wz, const float* __restrict__ Uz,
                                 const float* __restrict__ Wr, const float* __restrict__ Ur,
                                 unsigned short* __restrict__ Wcat) {
  const int total4 = 2048 * 2048 / 4;
  for (int i = blockIdx.x * blockDim.x + threadIdx.x; i < total4; i += gridDim.x * blockDim.x) {
    const int e = i * 4;
    const int n = e >> 11;
    const int c = e & 2047;
    const float* src;
    if (n < 1024) src = (c < 1024) ? (Wz + (size_t)n * 1024 + c) : (Uz + (size_t)n * 1024 + c - 1024);
    else          src = (c < 1024) ? (Wr + (size_t)(n - 1024) * 1024 + c) : (Ur + (size_t)(n - 1024) * 1024 + c - 1024);
    float4 v = *(const float4*)src;
    ushort4 o;
    o.x = f2bf(v.x); o.y = f2bf(v.y); o.z = f2bf(v.z); o.w = f2bf(v.w);
    *(ushort4*)(Wcat + e) = o;
  }
}

// Wva[n][0:1024] = bf16(Vh[n]); Wva[n][1024:2048] = bf16(Wh - Wh^T - gamma*I)[n]
__global__ void prep_VA_kernel(const float* __restrict__ Vh, const float* __restrict__ Wh,
                               unsigned short* __restrict__ Wva) {
  const int total4 = 1024 * 2048 / 4;
  for (int i = blockIdx.x * blockDim.x + threadIdx.x; i < total4; i += gridDim.x * blockDim.x) {
    const int e = i * 4;
    const int n = e >> 11;
    const int c = e & 2047;
    ushort4 o;
    if (c < 1024) {
      float4 v = *(const float4*)(Vh + (size_t)n * 1024 + c);
      o.x = f2bf(v.x); o.y = f2bf(v.y); o.z = f2bf(v.z); o.w = f2bf(v.w);
    } else {
      const int cc = c - 1024;
      float4 v = *(const float4*)(Wh + (size_t)n * 1024 + cc);
      float t0 = Wh[(size_t)(cc + 0) * 1024 + n];
      float t1 = Wh[(size_t)(cc + 1) * 1024 + n];
      float t2 = Wh[(size_t)(cc + 2) * 1024 + n];
      float t3 = Wh[(size_t)(cc + 3) * 1024 + n];
      o.x = f2bf(v.x - t0 - ((n == cc + 0) ? GAMMA : 0.0f));
      o.y = f2bf(v.y - t1 - ((n == cc + 1) ? GAMMA : 0.0f));
      o.z = f2bf(v.z - t2 - ((n == cc + 2) ? GAMMA : 0.0f));
      o.w = f2bf(v.w - t3 - ((n == cc + 3) ? GAMMA : 0.0f));
    }
    *(ushort4*)(Wva + e) = o;
  }
}

// In-place: Xcat[m][1024+n] = Zs_r[m][n] * Xcat[m][1024+n]   (Hr replaces h)
__global__ void phase3_kernel(const unsigned short* __restrict__ Zs,
                              unsigned short* __restrict__ Xcat) {
  const int total4 = BATCH * 1024 / 4;
  for (int i = blockIdx.x * blockDim.x + threadIdx.x; i < total4; i += gridDim.x * blockDim.x) {
    const int e = i * 4;
    const int m = e >> 10;
    const int n = e & 1023;
    ushort4 rs = *(const ushort4*)(Zs + (size_t)m * 2048 + 1024 + n);
    ushort4 hv = *(const ushort4*)(Xcat + (size_t)m * 2048 + 1024 + n);
    ushort4 o;
    o.x = f2bf(bf2f(rs.x) * bf2f(hv.x));
    o.y = f2bf(bf2f(rs.y) * bf2f(hv.y));
    o.z = f2bf(bf2f(rs.z) * bf2f(hv.z));
    o.w = f2bf(bf2f(rs.w) * bf2f(hv.w));
    *(ushort4*)(Xcat + (size_t)m * 2048 + 1024 + n) = o;
  }
}

// ---------- launch ----------
extern "C" void kernel_launch(void* const* d_in, const int* in_sizes, int n_in,
                              void* d_out, int out_size, void* d_ws, size_t ws_size,
                              hipStream_t stream) {
  const float* x   = (const float*)d_in[0];
  const float* h   = (const float*)d_in[1];
  const float* Wz  = (const float*)d_in[2];
  const float* bz  = (const float*)d_in[3];
  const float* Uz  = (const float*)d_in[4];
  const float* Wr  = (const float*)d_in[5];
  const float* br  = (const float*)d_in[6];
  const float* Ur  = (const float*)d_in[7];
  const float* Vh  = (const float*)d_in[8];
  const float* bh  = (const float*)d_in[9];
  const float* Wh  = (const float*)d_in[10];
  const float* eps = (const float*)d_in[11];
  float* out = (float*)d_out;

  char* ws = (char*)d_ws;
  size_t off = 0;
  unsigned short* Xcat = (unsigned short*)(ws + off); off += (size_t)BATCH * 2048 * 2;
  unsigned short* Wcat = (unsigned short*)(ws + off); off += (size_t)2048 * 2048 * 2;
  unsigned short* Wva  = (unsigned short*)(ws + off); off += (size_t)1024 * 2048 * 2;
  unsigned short* Zs   = (unsigned short*)(ws + off); off += (size_t)BATCH * 2048 * 2;

  dim3 blk(256);
  prep_x_kernel<<<2048, blk, 0, stream>>>(x, h, Xcat);
  prep_wcat_kernel<<<1024, blk, 0, stream>>>(Wz, Uz, Wr, Ur, Wcat);
  prep_VA_kernel<<<512, blk, 0, stream>>>(Vh, Wh, Wva);

  dim3 gblk(512);
  // GEMM1: Zs = sigmoid(Xcat @ Wcat^T + [bz|br])
  gemm_sig<<<(BATCH / 256) * (2048 / 256), gblk, 0, stream>>>(
      Xcat, Wcat, Zs, 2048, 2048, 2048, bz, br);
  // Hr = Zs_r * h, written in place into Xcat's h-half
  phase3_kernel<<<2048, blk, 0, stream>>>(Zs, Xcat);
  // GEMM23: out = h + eps*Zs_z*tanh([x|Hr] @ [Vh|A]^T + bh)
  gemm_combine2<<<(BATCH / 256) * (1024 / 256), gblk, 0, stream>>>(
      Xcat, Wva, 2048, 2048, 1024, Zs, bh, h, eps, out);
}

// Round 9
// 286.758 us; speedup vs baseline: 1.3507x; 1.3507x over previous
//
#include <hip/hip_runtime.h>
#include <hip/hip_bf16.h>
#include <stdint.h>

#define BATCH  16384
#define GAMMA  0.01f

using f32x4  = __attribute__((ext_vector_type(4))) float;
using bf16x8 = __attribute__((ext_vector_type(8))) __bf16;

#define MFMA16(a, b, c) __builtin_amdgcn_mfma_f32_16x16x32_bf16((a), (b), (c), 0, 0, 0)
#define BAR() asm volatile("s_barrier" ::: "memory")

// ---------- helpers ----------
__device__ __forceinline__ unsigned short f2bf(float f) {
  unsigned int u = __float_as_uint(f);
  unsigned int r = (u + 0x7fffu + ((u >> 16) & 1u)) >> 16;  // RNE
  return (unsigned short)r;
}
__device__ __forceinline__ float bf2f(unsigned short u) {
  return __uint_as_float(((unsigned int)u) << 16);
}
__device__ __forceinline__ float sigmoidf_(float x) {
  return 1.0f / (1.0f + __expf(-x));
}
__device__ __forceinline__ float tanhf_(float x) {
  float e = __expf(2.0f * x);
  return (e - 1.0f) / (e + 1.0f);
}
__device__ __forceinline__ void gload_lds16(const void* gsrc, void* ldst) {
  __builtin_amdgcn_global_load_lds(
      (const __attribute__((address_space(1))) void*)gsrc,
      (__attribute__((address_space(3))) void*)ldst, 16, 0, 0);
}

// =====================================================================
// R5-verified K-loop (952 TF measured, MfmaUtil 38%). DO NOT MODIFY.
// R3(restage)=565TF, R6(kslice)=942TF, R7(1-barrier)=838TF,
// R8(reg-pipeline)=715TF -- all four deviations measured worse.
//   P1: STAGE_A(cn,1,k1)  P2: STAGE_B(cn,0,k1)  P3: STAGE_B(cn,1,k1)
//   P4: STAGE_A(c,0,k2) + counted vmcnt(2); 2 barriers per phase.
// =====================================================================
#define GEMM_PREAMBLE_AND_KLOOP(X_, W_, lda_, K_, N_)                          \
  __shared__ unsigned short As[2 * 16384];                                     \
  __shared__ unsigned short Bs[2 * 16384];                                     \
  const int qq  = gridDim.x >> 3;                                              \
  const int swz = (blockIdx.x & 7) * qq + (blockIdx.x >> 3);                   \
  const int tiles_n = (N_) >> 8;                                               \
  const int brow = swz / tiles_n;                                              \
  const int bcol = swz % tiles_n;                                              \
  const int t    = threadIdx.x;                                                \
  const int lane = t & 63;                                                     \
  const int wave = t >> 6;                                                     \
  const int wm   = wave >> 2;                                                  \
  const int wn   = wave & 3;                                                   \
  const int lr   = lane & 15;                                                  \
  const int kq8  = (lane >> 4) * 8;                                            \
  const int sx   = (lr & 7) << 3;                                              \
  const int koff0 = kq8 ^ sx;                                                  \
  const int koff1 = (32 + kq8) ^ sx;                                           \
  const int aBase = (wm * 128 + lr) * 64;                                      \
  const int bBase = (wn * 64 + lr) * 64;                                       \
  const int srow = t >> 3;                                                     \
  const int sg   = (t & 7) ^ (srow & 7);                                       \
  const unsigned short* aSrc = (X_) + (size_t)(brow * 256 + srow) * (lda_) + sg * 8; \
  const unsigned short* bSrc = (W_) + (size_t)(bcol * 256 + srow) * (K_) + sg * 8;   \
  const int wofs = wave * 512;                                                 \
  auto STAGE_A = [&](int buf, int h, int k0) {                                 \
    gload_lds16(aSrc + (size_t)(h * 128) * (lda_) + k0,                        \
                As + buf * 16384 + (h * 128) * 64 + wofs);                     \
    gload_lds16(aSrc + (size_t)(h * 128 + 64) * (lda_) + k0,                   \
                As + buf * 16384 + (h * 128 + 64) * 64 + wofs);                \
  };                                                                           \
  auto STAGE_B = [&](int buf, int h, int k0) {                                 \
    gload_lds16(bSrc + (size_t)(h * 128) * (K_) + k0,                          \
                Bs + buf * 16384 + (h * 128) * 64 + wofs);                     \
    gload_lds16(bSrc + (size_t)(h * 128 + 64) * (K_) + k0,                     \
                Bs + buf * 16384 + (h * 128 + 64) * 64 + wofs);                \
  };                                                                           \
  GEMM_KLOOP_BODY(K_)

#define GEMM_KLOOP_BODY(K_)                                                    \
  f32x4 acc[8][4] = {};                                                        \
  bf16x8 aR[4][2], bR[4][2];                                                   \
  const int nt = (K_) >> 6;                                                    \
  STAGE_A(0, 0, 0); STAGE_A(0, 1, 0); STAGE_B(0, 0, 0); STAGE_B(0, 1, 0);      \
  STAGE_A(1, 0, 64);                                                           \
  asm volatile("s_waitcnt vmcnt(2)" ::: "memory");                             \
  BAR();                                                                       \
  for (int T = 0; T < nt; ++T) {                                               \
    const int c  = T & 1;                                                      \
    const int cn = c ^ 1;                                                      \
    const int k1 = (T + 1) << 6;                                               \
    const int k2 = (T + 2) << 6;                                               \
    const unsigned short* Ac = As + c * 16384;                                 \
    const unsigned short* Bc = Bs + c * 16384;                                 \
    /* P1 */                                                                   \
    _Pragma("unroll")                                                          \
    for (int i = 0; i < 4; ++i) {                                              \
      aR[i][0] = *(const bf16x8*)(Ac + aBase + i * 1024 + koff0);              \
      aR[i][1] = *(const bf16x8*)(Ac + aBase + i * 1024 + koff1);              \
    }                                                                          \
    _Pragma("unroll")                                                          \
    for (int j = 0; j < 2; ++j) {                                              \
      bR[j][0] = *(const bf16x8*)(Bc + bBase + j * 1024 + koff0);              \
      bR[j][1] = *(const bf16x8*)(Bc + bBase + j * 1024 + koff1);              \
    }                                                                          \
    if (T + 1 < nt) STAGE_A(cn, 1, k1);                                        \
    BAR();                                                                     \
    __builtin_amdgcn_s_setprio(1);                                             \
    _Pragma("unroll")                                                          \
    for (int i = 0; i < 4; ++i)                                                \
      _Pragma("unroll")                                                        \
      for (int j = 0; j < 2; ++j) {                                            \
        acc[i][j] = MFMA16(aR[i][0], bR[j][0], acc[i][j]);                     \
        acc[i][j] = MFMA16(aR[i][1], bR[j][1], acc[i][j]);                     \
      }                                                                        \
    __builtin_amdgcn_s_setprio(0);                                             \
    BAR();                                                                     \
    /* P2 */                                                                   \
    _Pragma("unroll")                                                          \
    for (int j = 2; j < 4; ++j) {                                              \
      bR[j][0] = *(const bf16x8*)(Bc + bBase + j * 1024 + koff0);              \
      bR[j][1] = *(const bf16x8*)(Bc + bBase + j * 1024 + koff1);              \
    }                                                                          \
    if (T + 1 < nt) STAGE_B(cn, 0, k1);                                        \
    BAR();                                                                     \
    __builtin_amdgcn_s_setprio(1);                                             \
    _Pragma("unroll")                                                          \
    for (int i = 0; i < 4; ++i)                                                \
      _Pragma("unroll")                                                        \
      for (int j = 2; j < 4; ++j) {                                            \
        acc[i][j] = MFMA16(aR[i][0], bR[j][0], acc[i][j]);                     \
        acc[i][j] = MFMA16(aR[i][1], bR[j][1], acc[i][j]);                     \
      }                                                                        \
    __builtin_amdgcn_s_setprio(0);                                             \
    BAR();                                                                     \
    /* P3 */                                                                   \
    _Pragma("unroll")                                                          \
    for (int i = 0; i < 4; ++i) {                                              \
      aR[i][0] = *(const bf16x8*)(Ac + aBase + (i + 4) * 1024 + koff0);        \
      aR[i][1] = *(const bf16x8*)(Ac + aBase + (i + 4) * 1024 + koff1);        \
    }                                                                          \
    if (T + 1 < nt) STAGE_B(cn, 1, k1);                                        \
    BAR();                                                                     \
    __builtin_amdgcn_s_setprio(1);                                             \
    _Pragma("unroll")                                                          \
    for (int i = 0; i < 4; ++i)                                                \
      _Pragma("unroll")                                                        \
      for (int j = 0; j < 2; ++j) {                                            \
        acc[i + 4][j] = MFMA16(aR[i][0], bR[j][0], acc[i + 4][j]);             \
        acc[i + 4][j] = MFMA16(aR[i][1], bR[j][1], acc[i + 4][j]);             \
      }                                                                        \
    __builtin_amdgcn_s_setprio(0);                                             \
    BAR();                                                                     \
    /* P4 */                                                                   \
    if (T + 2 < nt) STAGE_A(c, 0, k2);                                         \
    __builtin_amdgcn_s_setprio(1);                                             \
    _Pragma("unroll")                                                          \
    for (int i = 0; i < 4; ++i)                                                \
      _Pragma("unroll")                                                        \
      for (int j = 2; j < 4; ++j) {                                            \
        acc[i + 4][j] = MFMA16(aR[i][0], bR[j][0], acc[i + 4][j]);             \
        acc[i + 4][j] = MFMA16(aR[i][1], bR[j][1], acc[i + 4][j]);             \
      }                                                                        \
    __builtin_amdgcn_s_setprio(0);                                             \
    if (T + 2 < nt) { asm volatile("s_waitcnt vmcnt(2)" ::: "memory"); }       \
    else            { asm volatile("s_waitcnt vmcnt(0)" ::: "memory"); }       \
    BAR();                                                                     \
  }                                                                            \
  const int rbase = brow * 256 + wm * 128 + (lane >> 4) * 4;                   \
  const int cbase = bcol * 256 + wn * 64 + lr;

// Variant preamble with split A-source: rows' k<1024 from X1 (lda1),
// k>=1024 from X2 (lda 1024). Branch in STAGE_A is wave-uniform on k0.
#define GEMM_PREAMBLE_AND_KLOOP_SPLITA(X1_, X2_, lda1_, W_, K_, N_)            \
  __shared__ unsigned short As[2 * 16384];                                     \
  __shared__ unsigned short Bs[2 * 16384];                                     \
  const int qq  = gridDim.x >> 3;                                              \
  const int swz = (blockIdx.x & 7) * qq + (blockIdx.x >> 3);                   \
  const int tiles_n = (N_) >> 8;                                               \
  const int brow = swz / tiles_n;                                              \
  const int bcol = swz % tiles_n;                                              \
  const int t    = threadIdx.x;                                                \
  const int lane = t & 63;                                                     \
  const int wave = t >> 6;                                                     \
  const int wm   = wave >> 2;                                                  \
  const int wn   = wave & 3;                                                   \
  const int lr   = lane & 15;                                                  \
  const int kq8  = (lane >> 4) * 8;                                            \
  const int sx   = (lr & 7) << 3;                                              \
  const int koff0 = kq8 ^ sx;                                                  \
  const int koff1 = (32 + kq8) ^ sx;                                           \
  const int aBase = (wm * 128 + lr) * 64;                                      \
  const int bBase = (wn * 64 + lr) * 64;                                       \
  const int srow = t >> 3;                                                     \
  const int sg   = (t & 7) ^ (srow & 7);                                       \
  const unsigned short* aSrc1 = (X1_) + (size_t)(brow * 256 + srow) * (lda1_) + sg * 8; \
  const unsigned short* aSrc2 = (X2_) + (size_t)(brow * 256 + srow) * 1024 + sg * 8;    \
  const unsigned short* bSrc  = (W_)  + (size_t)(bcol * 256 + srow) * (K_) + sg * 8;    \
  const int wofs = wave * 512;                                                 \
  auto STAGE_A = [&](int buf, int h, int k0) {                                 \
    if (k0 < 1024) {                                                           \
      gload_lds16(aSrc1 + (size_t)(h * 128) * (lda1_) + k0,                    \
                  As + buf * 16384 + (h * 128) * 64 + wofs);                   \
      gload_lds16(aSrc1 + (size_t)(h * 128 + 64) * (lda1_) + k0,               \
                  As + buf * 16384 + (h * 128 + 64) * 64 + wofs);              \
    } else {                                                                   \
      gload_lds16(aSrc2 + (size_t)(h * 128) * 1024 + (k0 - 1024),              \
                  As + buf * 16384 + (h * 128) * 64 + wofs);                   \
      gload_lds16(aSrc2 + (size_t)(h * 128 + 64) * 1024 + (k0 - 1024),         \
                  As + buf * 16384 + (h * 128 + 64) * 64 + wofs);              \
    }                                                                          \
  };                                                                           \
  auto STAGE_B = [&](int buf, int h, int k0) {                                 \
    gload_lds16(bSrc + (size_t)(h * 128) * (K_) + k0,                          \
                Bs + buf * 16384 + (h * 128) * 64 + wofs);                     \
    gload_lds16(bSrc + (size_t)(h * 128 + 64) * (K_) + k0,                     \
                Bs + buf * 16384 + (h * 128 + 64) * 64 + wofs);                \
  };                                                                           \
  GEMM_KLOOP_BODY(K_)

// ---------- GEMM1: gates. z-blocks -> Zs = sigmoid(z_pre+bz);
//                          r-blocks -> Hr = sigmoid(r_pre+br)*h ----------
__global__ __launch_bounds__(512, 2) void gemm_sig(
    const unsigned short* __restrict__ X, const unsigned short* __restrict__ W,
    unsigned short* __restrict__ Zs, unsigned short* __restrict__ Hr,
    int lda, int K, int N,
    const float* __restrict__ bz, const float* __restrict__ br,
    const float* __restrict__ h) {
  GEMM_PREAMBLE_AND_KLOOP(X, W, lda, K, N)
  if (bcol * 256 < 1024) {
#pragma unroll
    for (int i = 0; i < 8; ++i)
#pragma unroll
      for (int j = 0; j < 4; ++j)
#pragma unroll
        for (int q = 0; q < 4; ++q) {
          const int col = cbase + j * 16;
          Zs[(size_t)(rbase + i * 16 + q) * 1024 + col] =
              f2bf(sigmoidf_(acc[i][j][q] + bz[col]));
        }
  } else {
#pragma unroll
    for (int i = 0; i < 8; ++i)
#pragma unroll
      for (int j = 0; j < 4; ++j)
#pragma unroll
        for (int q = 0; q < 4; ++q) {
          const int c2 = cbase + j * 16 - 1024;
          const size_t e = (size_t)(rbase + i * 16 + q) * 1024 + c2;
          Hr[e] = f2bf(sigmoidf_(acc[i][j][q] + br[c2]) * h[e]);
        }
  }
}

// ---------- GEMM23 merged: acc = [x|Hr] @ [Vh|A]^T (split A-source) --------
// out = h + eps * Zs * tanh(acc + bh)
__global__ __launch_bounds__(512, 2) void gemm_combine2(
    const unsigned short* __restrict__ Xc, const unsigned short* __restrict__ Hr,
    const unsigned short* __restrict__ W, int K, int N,
    const unsigned short* __restrict__ Zs,
    const float* __restrict__ bh, const float* __restrict__ h,
    const float* __restrict__ epsp, float* __restrict__ fout) {
  GEMM_PREAMBLE_AND_KLOOP_SPLITA(Xc, Hr, 2048, W, K, N)
  const float eps = epsp[0];
#pragma unroll
  for (int i = 0; i < 8; ++i)
#pragma unroll
    for (int j = 0; j < 4; ++j)
#pragma unroll
      for (int q = 0; q < 4; ++q) {
        const int row = rbase + i * 16 + q;
        const int col = cbase + j * 16;
        const size_t e = (size_t)row * 1024 + col;
        const float tv = tanhf_(acc[i][j][q] + bh[col]);
        fout[e] = h[e] + eps * bf2f(Zs[e]) * tv;
      }
}

// ---------- prep kernels ----------
__global__ void prep_x_kernel(const float* __restrict__ x, const float* __restrict__ h,
                              unsigned short* __restrict__ Xcat) {
  const int total4 = BATCH * 2048 / 4;
  for (int i = blockIdx.x * blockDim.x + threadIdx.x; i < total4; i += gridDim.x * blockDim.x) {
    const int e = i * 4;
    const int m = e >> 11;
    const int c = e & 2047;
    float4 v = (c < 1024) ? *(const float4*)(x + (size_t)m * 1024 + c)
                          : *(const float4*)(h + (size_t)m * 1024 + (c - 1024));
    ushort4 o;
    o.x = f2bf(v.x); o.y = f2bf(v.y); o.z = f2bf(v.z); o.w = f2bf(v.w);
    *(ushort4*)(Xcat + e) = o;
  }
}

__global__ void prep_wcat_kernel(const float* __restrict__ Wz, const float* __restrict__ Uz,
                                 const float* __restrict__ Wr, const float* __restrict__ Ur,
                                 unsigned short* __restrict__ Wcat) {
  const int total4 = 2048 * 2048 / 4;
  for (int i = blockIdx.x * blockDim.x + threadIdx.x; i < total4; i += gridDim.x * blockDim.x) {
    const int e = i * 4;
    const int n = e >> 11;
    const int c = e & 2047;
    const float* src;
    if (n < 1024) src = (c < 1024) ? (Wz + (size_t)n * 1024 + c) : (Uz + (size_t)n * 1024 + c - 1024);
    else          src = (c < 1024) ? (Wr + (size_t)(n - 1024) * 1024 + c) : (Ur + (size_t)(n - 1024) * 1024 + c - 1024);
    float4 v = *(const float4*)src;
    ushort4 o;
    o.x = f2bf(v.x); o.y = f2bf(v.y); o.z = f2bf(v.z); o.w = f2bf(v.w);
    *(ushort4*)(Wcat + e) = o;
  }
}

// Wva[n][0:1024] = bf16(Vh[n]); Wva[n][1024:2048] = bf16(Wh - Wh^T - gamma*I)[n]
__global__ void prep_VA_kernel(const float* __restrict__ Vh, const float* __restrict__ Wh,
                               unsigned short* __restrict__ Wva) {
  const int total4 = 1024 * 2048 / 4;
  for (int i = blockIdx.x * blockDim.x + threadIdx.x; i < total4; i += gridDim.x * blockDim.x) {
    const int e = i * 4;
    const int n = e >> 11;
    const int c = e & 2047;
    ushort4 o;
    if (c < 1024) {
      float4 v = *(const float4*)(Vh + (size_t)n * 1024 + c);
      o.x = f2bf(v.x); o.y = f2bf(v.y); o.z = f2bf(v.z); o.w = f2bf(v.w);
    } else {
      const int cc = c - 1024;
      float4 v = *(const float4*)(Wh + (size_t)n * 1024 + cc);
      float t0 = Wh[(size_t)(cc + 0) * 1024 + n];
      float t1 = Wh[(size_t)(cc + 1) * 1024 + n];
      float t2 = Wh[(size_t)(cc + 2) * 1024 + n];
      float t3 = Wh[(size_t)(cc + 3) * 1024 + n];
      o.x = f2bf(v.x - t0 - ((n == cc + 0) ? GAMMA : 0.0f));
      o.y = f2bf(v.y - t1 - ((n == cc + 1) ? GAMMA : 0.0f));
      o.z = f2bf(v.z - t2 - ((n == cc + 2) ? GAMMA : 0.0f));
      o.w = f2bf(v.w - t3 - ((n == cc + 3) ? GAMMA : 0.0f));
    }
    *(ushort4*)(Wva + e) = o;
  }
}

// ---------- launch ----------
extern "C" void kernel_launch(void* const* d_in, const int* in_sizes, int n_in,
                              void* d_out, int out_size, void* d_ws, size_t ws_size,
                              hipStream_t stream) {
  const float* x   = (const float*)d_in[0];
  const float* h   = (const float*)d_in[1];
  const float* Wz  = (const float*)d_in[2];
  const float* bz  = (const float*)d_in[3];
  const float* Uz  = (const float*)d_in[4];
  const float* Wr  = (const float*)d_in[5];
  const float* br  = (const float*)d_in[6];
  const float* Ur  = (const float*)d_in[7];
  const float* Vh  = (const float*)d_in[8];
  const float* bh  = (const float*)d_in[9];
  const float* Wh  = (const float*)d_in[10];
  const float* eps = (const float*)d_in[11];
  float* out = (float*)d_out;

  char* ws = (char*)d_ws;
  size_t off = 0;
  unsigned short* Xcat = (unsigned short*)(ws + off); off += (size_t)BATCH * 2048 * 2;
  unsigned short* Wcat = (unsigned short*)(ws + off); off += (size_t)2048 * 2048 * 2;
  unsigned short* Wva  = (unsigned short*)(ws + off); off += (size_t)1024 * 2048 * 2;
  unsigned short* Zs   = (unsigned short*)(ws + off); off += (size_t)BATCH * 1024 * 2;
  unsigned short* Hr   = (unsigned short*)(ws + off); off += (size_t)BATCH * 1024 * 2;

  dim3 blk(256);
  prep_x_kernel<<<2048, blk, 0, stream>>>(x, h, Xcat);
  prep_wcat_kernel<<<1024, blk, 0, stream>>>(Wz, Uz, Wr, Ur, Wcat);
  prep_VA_kernel<<<512, blk, 0, stream>>>(Vh, Wh, Wva);

  dim3 gblk(512);
  // GEMM1: z-blocks -> Zs, r-blocks -> Hr (fused sigmoid/mul epilogues)
  gemm_sig<<<(BATCH / 256) * (2048 / 256), gblk, 0, stream>>>(
      Xcat, Wcat, Zs, Hr, 2048, 2048, 2048, bz, br, h);
  // GEMM23: out = h + eps*Zs*tanh([x|Hr] @ [Vh|A]^T + bh)
  gemm_combine2<<<(BATCH / 256) * (1024 / 256), gblk, 0, stream>>>(
      Xcat, Hr, Wva, 2048, 1024, Zs, bh, h, eps, out);
}